// Round 10
// baseline (12026.313 us; speedup 1.0000x reference)
//
#include <hip/hip_runtime.h>

#define B_ 32
#define S_ 512
#define H_ 1024
#define L_ 3
#define BH (B_*H_)     // 32768
#define NBLK 512
#define PLANE 32768    // u16 elems in one A-frag-packed 32x1024 activation plane
#define CNT_BYTES (6*512*32*4)   // cnt[kind2][g3][t512], 128B apart

typedef __attribute__((ext_vector_type(8))) short short8;
typedef __attribute__((ext_vector_type(4))) float f4;

__device__ __forceinline__ unsigned short f2bf(float f){
  unsigned int u = __float_as_uint(f);
  u += 0x7fffu + ((u >> 16) & 1u);   // RNE
  return (unsigned short)(u >> 16);
}
__device__ __forceinline__ float sigmoidf_(float x){
  return 1.0f / (1.0f + __expf(-x));
}
// offset (u16) of element (batch-row b, feature n) inside an A-frag-packed plane
// plane layout: [mh(2)][kb(32)][lane(64)][j(8)], lane = quad*16 + row
__device__ __forceinline__ int afrag_off(int b, int n){
  int mh = b >> 4, row = b & 15;
  int kb = n >> 5, quad = (n >> 3) & 3, j = n & 7;
  return (((mh * 32 + kb) * 64) + quad * 16 + row) * 8 + j;
}

// -------- device-coherent (agent scope) helpers -----------------------------
template<bool DC>
__device__ __forceinline__ short8 ldA(const unsigned short* p){
  short8 v;
  if constexpr (DC)
    asm volatile("global_load_dwordx4 %0, %1, off sc1" : "=&v"(v) : "v"(p));
  else
    asm volatile("global_load_dwordx4 %0, %1, off" : "=&v"(v) : "v"(p));
  return v;
}
template<int N>
__device__ __forceinline__ void waitv(){
  asm volatile("s_waitcnt vmcnt(%0)" :: "i"(N));
  __builtin_amdgcn_sched_barrier(0);   // rule #18: keep consumers below the wait
}
__device__ __forceinline__ float ldf_dc(const float* p){
  return __hip_atomic_load(p, __ATOMIC_RELAXED, __HIP_MEMORY_SCOPE_AGENT);
}
__device__ __forceinline__ void stf_dc(float* p, float v){
  __hip_atomic_store(p, v, __ATOMIC_RELAXED, __HIP_MEMORY_SCOPE_AGENT);
}
__device__ __forceinline__ void stu16_dc(unsigned short* p, unsigned short v){
  __hip_atomic_store(p, v, __ATOMIC_RELAXED, __HIP_MEMORY_SCOPE_AGENT);
}

// ---------------- dataflow counters -----------------------------------------
// cnt(kind b: 0=A 1=B, layer g, timestep t) at ((b*3+g)*512+t)*32 uints.
// Producers: __syncthreads (drains all waves' DC stores to IC) then leader
// fetch_add. Consumers: leader polls relaxed agent loads, then __syncthreads
// releases the block. Targets: A groups = 128 blocks, B groups = 64 blocks.
__device__ __forceinline__ unsigned* cptr(unsigned* cnt, int b, int g, int t){
  return cnt + (size_t)((b * 3 + g) * 512 + t) * 32;
}
__device__ __forceinline__ void waitc(unsigned* c, unsigned tgt){
  while (__hip_atomic_load(c, __ATOMIC_RELAXED, __HIP_MEMORY_SCOPE_AGENT) < tgt)
    __builtin_amdgcn_s_sleep(1);
}
__device__ __forceinline__ void signalc(unsigned* c){
  __hip_atomic_fetch_add(c, 1u, __ATOMIC_RELAXED, __HIP_MEMORY_SCOPE_AGENT);
}

// ---------------- prep: pack weights in MFMA-fragment order -----------------
__global__ void prep_WA_packed(const float* __restrict__ Wx, const float* __restrict__ Wz,
                               const float* __restrict__ Wr, const float* __restrict__ Wh,
                               unsigned short* __restrict__ WAp){
  int idx = blockIdx.x * blockDim.x + threadIdx.x;  // 384*64*64 exact
  int lane = idx & 63;
  int kb = (idx >> 6) & 63;
  int tile = idx >> 12;
  int g = tile >> 7, jt = tile & 127;
  int quad = lane >> 4, l15 = lane & 15;
  int n = jt * 16 + l15;
  int k0 = kb * 32 + quad * 8;
  int col = n & 1023;
  const float* W = (k0 < 1024) ? ((n < 1024) ? Wx : Wr) : ((n < 1024) ? Wz : Wh);
  const float* src = W + ((size_t)g * 1024 + (k0 & 1023)) * 1024 + col;
  short8 v;
  #pragma unroll
  for (int j = 0; j < 8; ++j) v[j] = (short)f2bf(src[(size_t)j * 1024]);
  *(short8*)(WAp + (size_t)idx * 8) = v;
}

__global__ void prep_WB_packed(const float* __restrict__ Wg, const float* __restrict__ Whg,
                               unsigned short* __restrict__ WBp){
  int idx = blockIdx.x * blockDim.x + threadIdx.x;  // 192*64*64 exact
  int lane = idx & 63;
  int kb = (idx >> 6) & 63;
  int tile = idx >> 12;
  int g = tile >> 6, jt = tile & 63;
  int quad = lane >> 4, l15 = lane & 15;
  int n = jt * 16 + l15;
  int k0 = kb * 32 + quad * 8;
  const float* W = (k0 < 1024) ? Wg : Whg;
  const float* src = W + ((size_t)g * 1024 + (k0 & 1023)) * 1024 + n;
  short8 v;
  #pragma unroll
  for (int j = 0; j < 8; ++j) v[j] = (short)f2bf(src[(size_t)j * 1024]);
  *(short8*)(WBp + (size_t)idx * 8) = v;
}

__global__ void prep_Wout_packed(const float* __restrict__ Wout,
                                 unsigned short* __restrict__ WoutP){
  int idx = blockIdx.x * blockDim.x + threadIdx.x;  // 64*32*64 exact
  int lane = idx & 63;
  int kb = (idx >> 6) & 31;
  int tile = idx >> 11;
  int quad = lane >> 4, l15 = lane & 15;
  int n = tile * 16 + l15;
  int k0 = kb * 32 + quad * 8;
  const float* src = Wout + (size_t)k0 * 1024 + n;
  short8 v;
  #pragma unroll
  for (int j = 0; j < 8; ++j) v[j] = (short)f2bf(src[(size_t)j * 1024]);
  *(short8*)(WoutP + (size_t)idx * 8) = v;
}

__global__ void prep_X_packed(const float* __restrict__ x, unsigned short* __restrict__ Xp){
  size_t idx = (size_t)blockIdx.x * blockDim.x + threadIdx.x;  // 512*32768 exact
  int j = (int)(idx & 7);
  int lane = (int)((idx >> 3) & 63);
  int kb = (int)((idx >> 9) & 31);
  int mh = (int)((idx >> 14) & 1);
  int t = (int)(idx >> 15);
  int b = mh * 16 + (lane & 15);
  int i = kb * 32 + (lane >> 4) * 8 + j;
  Xp[idx] = f2bf(x[((size_t)b * S_ + t) * 1024 + i]);
}

__global__ void prep_H0_kernel(const float* __restrict__ h0,
                               unsigned short* __restrict__ HTb, float* __restrict__ HTf,
                               unsigned short* __restrict__ hfinp){
  int idx = blockIdx.x * blockDim.x + threadIdx.x;  // 3*32*1024 exact
  int h = idx & 1023;
  int b = (idx >> 10) & 31;
  int v = idx >> 15;
  float val = h0[((size_t)b * L_ + v) * 1024 + h];
  HTb[idx] = f2bf(val);
  HTf[idx] = val;                              // ring slot v&7 == v for v<3
  hfinp[(size_t)v * PLANE + afrag_off(b, h)] = f2bf(val);
}

// ------- pipelined 64-step GEMM, LDS weights (batch 8, depth 4) -------------
template<bool DCI>
__device__ __forceinline__ f4 gemm64_lds(const unsigned short* __restrict__ inp,
                                         const unsigned short* __restrict__ st,
                                         const unsigned short* w,   // LDS only
                                         int mh, int lane){
  const unsigned short* pi = inp + mh * 16384 + lane * 8;
  const unsigned short* ps = st  + mh * 16384 + lane * 8;
  short8 ab[4][8];
  #pragma unroll
  for (int b = 0; b < 4; ++b)
    #pragma unroll
    for (int j = 0; j < 8; ++j)
      ab[b][j] = ldA<DCI>(pi + (size_t)(b * 8 + j) * 512);
  f4 acc = {0.f, 0.f, 0.f, 0.f};
  #pragma unroll
  for (int b = 0; b < 4; ++b){
    short8 wv[8];                              // ds_reads issued BEFORE the wait
    #pragma unroll
    for (int j = 0; j < 8; ++j)
      wv[j] = *(const short8*)(w + (size_t)((b * 8 + j) * 64 + lane) * 8);
    waitv<24>();                               // batch b (inp) landed
    #pragma unroll
    for (int j = 0; j < 8; ++j)
      acc = __builtin_amdgcn_mfma_f32_16x16x32_bf16(ab[b][j], wv[j], acc, 0, 0, 0);
    #pragma unroll
    for (int j = 0; j < 8; ++j)                // refill slot with st batch b
      ab[b][j] = ldA<true>(ps + (size_t)(b * 8 + j) * 512);
  }
  #pragma unroll
  for (int b = 0; b < 4; ++b){
    short8 wv[8];
    #pragma unroll
    for (int j = 0; j < 8; ++j)
      wv[j] = *(const short8*)(w + (size_t)((32 + b * 8 + j) * 64 + lane) * 8);
    if (b == 0) waitv<24>();
    else if (b == 1) waitv<16>();
    else if (b == 2) waitv<8>();
    else waitv<0>();
    #pragma unroll
    for (int j = 0; j < 8; ++j)
      acc = __builtin_amdgcn_mfma_f32_16x16x32_bf16(ab[b][j], wv[j], acc, 0, 0, 0);
  }
  return acc;
}

// ------- pipelined GEMM for streamed global weights (dual-role blocks) ------
__device__ __forceinline__ f4 gemm64_gw(const unsigned short* __restrict__ inp,
                                        const unsigned short* __restrict__ st,
                                        const unsigned short* __restrict__ wg,
                                        int mh, int lane){
  const unsigned short* pi = inp + mh * 16384 + lane * 8;
  const unsigned short* ps = st  + mh * 16384 + lane * 8;
  const unsigned short* pw = wg + lane * 8;
  short8 ab[2][8], wb[2][8];
  #pragma unroll
  for (int b = 0; b < 2; ++b){
    #pragma unroll
    for (int j = 0; j < 8; ++j) ab[b][j] = ldA<true>(pi + (size_t)(b * 8 + j) * 512);
    #pragma unroll
    for (int j = 0; j < 8; ++j) wb[b][j] = ldA<false>(pw + (size_t)(b * 8 + j) * 512);
  }
  f4 acc = {0.f, 0.f, 0.f, 0.f};
  #pragma unroll
  for (int b = 0; b < 8; ++b){
    if (b < 7) waitv<16>(); else waitv<0>();
    #pragma unroll
    for (int j = 0; j < 8; ++j)
      acc = __builtin_amdgcn_mfma_f32_16x16x32_bf16(ab[b & 1][j], wb[b & 1][j], acc, 0, 0, 0);
    if (b < 6){
      const int nb = b + 2;
      #pragma unroll
      for (int j = 0; j < 8; ++j){
        if (nb < 4) ab[b & 1][j] = ldA<true>(pi + (size_t)(nb * 8 + j) * 512);
        else        ab[b & 1][j] = ldA<true>(ps + (size_t)((nb - 4) * 8 + j) * 512);
      }
      #pragma unroll
      for (int j = 0; j < 8; ++j)
        wb[b & 1][j] = ldA<false>(pw + (size_t)(nb * 8 + j) * 512);
    }
  }
  return acc;
}

// ---------------- role bodies (identical math to R8) ------------------------
__device__ __forceinline__ void A_body(int gA, int jtA, int mh, int lane, int quad, int l15,
    int t, const unsigned short* Xp, const unsigned short* hL0p, const unsigned short* hL1p,
    const unsigned short* hfinp, const float* HTf, float* zbuf, unsigned short* rsp,
    const unsigned short* ldsw, float biasA){
  int tm = t & 3, v = t + gA;
  const unsigned short* inp = (gA == 0) ? Xp + (size_t)t * PLANE
                            : (gA == 1) ? hL0p + (size_t)tm * PLANE
                                        : hL1p + (size_t)tm * PLANE;
  const unsigned short* st = hfinp + (size_t)(v & 7) * PLANE;
  f4 acc = (gA == 0) ? gemm64_lds<false>(inp, st, ldsw, mh, lane)
                     : gemm64_lds<true >(inp, st, ldsw, mh, lane);
  int n2 = jtA * 16 + l15;
  const float* sf = HTf + (size_t)(v & 7) * BH;
  if (jtA < 64){
    float* zb = zbuf + (size_t)(gA * 4 + tm) * BH;
    #pragma unroll
    for (int r = 0; r < 4; ++r){
      int b = mh * 16 + quad * 4 + r;
      stf_dc(zb + b * H_ + n2, sigmoidf_(acc[r] + biasA));
    }
  } else {
    int n = n2 - 1024;
    unsigned short* rp = rsp + (size_t)(gA * 4 + tm) * PLANE;
    #pragma unroll
    for (int r = 0; r < 4; ++r){
      int b = mh * 16 + quad * 4 + r;
      float sv = ldf_dc(sf + b * H_ + n);
      stu16_dc(rp + afrag_off(b, n), f2bf(sigmoidf_(acc[r] + biasA) * sv));
    }
  }
}

__device__ __forceinline__ void B_body(int gB, int jtB, int mh, int lane, int quad, int l15,
    int t, const unsigned short* Xp, unsigned short* hL0p, unsigned short* hL1p,
    unsigned short* hfinp, unsigned short* HTb, float* HTf, const float* zbuf,
    const unsigned short* rsp, const unsigned short* ldsw, const unsigned short* wBg,
    float biasB){
  int tm = t & 3, v = t + gB;
  const unsigned short* inp = (gB == 0) ? Xp + (size_t)t * PLANE
                            : (gB == 1) ? hL0p + (size_t)tm * PLANE
                                        : hL1p + (size_t)tm * PLANE;
  const unsigned short* rp = rsp + (size_t)(gB * 4 + tm) * PLANE;
  f4 acc;
  if (wBg)          acc = gemm64_gw(inp, rp, wBg, mh, lane);
  else if (gB == 0) acc = gemm64_lds<false>(inp, rp, ldsw, mh, lane);
  else              acc = gemm64_lds<true >(inp, rp, ldsw, mh, lane);
  int n = jtB * 16 + l15;
  const float* sf = HTf + (size_t)(v & 7) * BH;
  const float* zb = zbuf + (size_t)(gB * 4 + tm) * BH;
  #pragma unroll
  for (int r = 0; r < 4; ++r){
    int b = mh * 16 + quad * 4 + r;
    float gg = tanhf(acc[r] + biasB);
    float z = ldf_dc(zb + b * H_ + n);
    float sv = ldf_dc(sf + b * H_ + n);
    float h = z * sv + (1.f - z) * gg;
    unsigned short hb = f2bf(h);
    if (gB == 2){
      stf_dc(HTf + (size_t)((t + 3) & 7) * BH + b * H_ + n, h);
      HTb[(size_t)(t + 3) * BH + b * H_ + n] = hb;   // plain: read post-kernel only
      stu16_dc(hfinp + (size_t)((t + 3) & 7) * PLANE + afrag_off(b, n), hb);
    } else if (gB == 0){
      stu16_dc(hL0p + (size_t)tm * PLANE + afrag_off(b, n), hb);
    } else {
      stu16_dc(hL1p + (size_t)tm * PLANE + afrag_off(b, n), hb);
    }
  }
}

// ---------------- persistent recurrence: dataflow-synced --------------------
// R8 block layout: blocks 0..383 A-tiles (g=blk>>7, jt=blk&127, LDS weights);
// 384..511 B-tiles g=0,1 (LDS); 320..383 dual-role: also B g=2 (streamed W).
// Dependency edges (RAW + WAR from ring depths 4 / 8):
//  A(g,t): B(g-1,t) | B(2,t+g-3) | B(g,t-4)
//  B(g,t): A(g,t) | B(g-1,t) | B(2,t+g-3) |
//          g<2: A(g+1,t-4), B(g+1,t-4)
//          g=2: A(0,t-5), A(1,t-6), A(2,t-7), B(0,t-5), B(1,t-6)
__global__ __launch_bounds__(128) void gru_persist(
    const unsigned short* __restrict__ WAp, const unsigned short* __restrict__ WBp,
    const unsigned short* __restrict__ Xp,
    unsigned short* __restrict__ hL0p, unsigned short* __restrict__ hL1p,
    unsigned short* __restrict__ hfinp,
    unsigned short* __restrict__ HTb, float* __restrict__ HTf,
    float* __restrict__ zbuf, unsigned short* __restrict__ rsp,
    const float* __restrict__ bz, const float* __restrict__ br,
    const float* __restrict__ bg, unsigned* cnt)
{
  __shared__ unsigned short ldsw[32768];   // 64 KB weight tile
  const int blk = blockIdx.x;
  const int lane = threadIdx.x & 63;
  const int mh = threadIdx.x >> 6;
  const int quad = lane >> 4, l15 = lane & 15;

  // bootstrap: copy this block's weight tile into LDS (coalesced 16B/lane)
  {
    const unsigned short* src = (blk < 384) ? WAp + (size_t)blk * 32768
                                            : WBp + (size_t)(blk - 384) * 32768;
    for (int i = threadIdx.x; i < 4096; i += 128)
      *(short8*)(ldsw + (size_t)i * 8) = *(const short8*)(src + (size_t)i * 8);
  }
  __syncthreads();

  const int gA = blk >> 7, jtA = blk & 127;
  int gB = -1, jtB = 0;
  const unsigned short* wBg = nullptr;     // non-null => stream B weights from global
  if (blk >= 384){ gB = (blk - 384) >> 6; jtB = (blk - 384) & 63; }
  else if (blk >= 320){ gB = 2; jtB = blk - 320; wBg = WBp + (size_t)(128 + (blk - 320)) * 32768; }

  float biasA = 0.f, biasB = 0.f;
  if (blk < 384){
    int n2 = jtA * 16 + l15;
    biasA = (jtA < 64) ? bz[gA * H_ + n2] : br[gA * H_ + n2 - 1024];
  }
  if (gB >= 0) biasB = bg[gB * H_ + jtB * 16 + l15];

  if (blk < 320){
    // ---------------- pure A block ----------------
    for (int t = 0; t < S_; ++t){
      if (threadIdx.x == 0){
        if (gA > 0) waitc(cptr(cnt, 1, gA - 1, t), 64);
        int w = t + gA - 3;
        if (w >= 0) waitc(cptr(cnt, 1, 2, w), 64);
        if (t >= 4) waitc(cptr(cnt, 1, gA, t - 4), 64);
      }
      __syncthreads();
      A_body(gA, jtA, mh, lane, quad, l15, t, Xp, hL0p, hL1p, hfinp, HTf, zbuf, rsp,
             ldsw, biasA);
      __syncthreads();   // drains both waves' stores to IC
      if (threadIdx.x == 0) signalc(cptr(cnt, 0, gA, t));
    }
  } else if (blk < 384){
    // ---------------- dual-role: A(2,t) then B(2,t) ----------------
    for (int t = 0; t < S_; ++t){
      if (threadIdx.x == 0){
        waitc(cptr(cnt, 1, 1, t), 64);              // B(1,t): inp plane + A dep
        if (t >= 1) waitc(cptr(cnt, 1, 2, t - 1), 64);  // hfinp/HTf slot v=t+2
        if (t >= 4) waitc(cptr(cnt, 1, 2, t - 4), 64);  // WAR zbuf/rsp layer2
      }
      __syncthreads();
      A_body(2, jtA, mh, lane, quad, l15, t, Xp, hL0p, hL1p, hfinp, HTf, zbuf, rsp,
             ldsw, biasA);
      __syncthreads();
      if (threadIdx.x == 0){
        signalc(cptr(cnt, 0, 2, t));
        waitc(cptr(cnt, 0, 2, t), 128);             // all A(2,t): rsp/zbuf full
        if (t >= 5) waitc(cptr(cnt, 0, 0, t - 5), 128);  // WAR hfinp/HTf slot
        if (t >= 6) waitc(cptr(cnt, 0, 1, t - 6), 128);
        if (t >= 7) waitc(cptr(cnt, 0, 2, t - 7), 128);
        if (t >= 5) waitc(cptr(cnt, 1, 0, t - 5), 64);
        if (t >= 6) waitc(cptr(cnt, 1, 1, t - 6), 64);
      }
      __syncthreads();
      B_body(2, jtB, mh, lane, quad, l15, t, Xp, hL0p, hL1p, hfinp, HTb, HTf, zbuf, rsp,
             ldsw, wBg, biasB);
      __syncthreads();
      if (threadIdx.x == 0) signalc(cptr(cnt, 1, 2, t));
    }
  } else {
    // ---------------- pure B block (g = 0 or 1) ----------------
    for (int t = 0; t < S_; ++t){
      if (threadIdx.x == 0){
        waitc(cptr(cnt, 0, gB, t), 128);            // A(g,t): rsp/zbuf
        if (gB > 0) waitc(cptr(cnt, 1, gB - 1, t), 64);
        int w = t + gB - 3;
        if (w >= 0) waitc(cptr(cnt, 1, 2, w), 64);  // HTf slot v=t+g
        if (t >= 4){                                // WAR hL{g}p slot t&3
          waitc(cptr(cnt, 0, gB + 1, t - 4), 128);
          waitc(cptr(cnt, 1, gB + 1, t - 4), 64);
        }
      }
      __syncthreads();
      B_body(gB, jtB, mh, lane, quad, l15, t, Xp, hL0p, hL1p, hfinp, HTb, HTf, zbuf, rsp,
             ldsw, nullptr, biasB);
      __syncthreads();
      if (threadIdx.x == 0) signalc(cptr(cnt, 1, gB, t));
    }
  }
}

// ---------------- epilogue: Y = HT @ Wout + bout ----------------------------
__global__ __launch_bounds__(256) void out_proj_kernel(
    const unsigned short* __restrict__ HTb, const unsigned short* __restrict__ WoutP,
    const float* __restrict__ bout, float* __restrict__ Y){
  int tstep = blockIdx.x >> 2;
  int nblk  = blockIdx.x & 3;
  int wave = threadIdx.x >> 6, lane = threadIdx.x & 63;
  int quad = lane >> 4, l15 = lane & 15;
  const unsigned short* A = HTb + (size_t)(tstep + 3) * BH;
  f4 acc[2][4] = {};
  for (int kk = 0; kk < 32; ++kk){
    int k0 = kk * 32 + quad * 8;
    short8 a0 = *(const short8*)(A + l15 * H_ + k0);
    short8 a1 = *(const short8*)(A + (l15 + 16) * H_ + k0);
    #pragma unroll
    for (int nt = 0; nt < 4; ++nt){
      int tile = nblk * 16 + wave * 4 + nt;
      short8 bv = ((const short8*)WoutP)[((size_t)tile * 32 + kk) * 64 + lane];
      acc[0][nt] = __builtin_amdgcn_mfma_f32_16x16x32_bf16(a0, bv, acc[0][nt], 0, 0, 0);
      acc[1][nt] = __builtin_amdgcn_mfma_f32_16x16x32_bf16(a1, bv, acc[1][nt], 0, 0, 0);
    }
  }
  #pragma unroll
  for (int mt = 0; mt < 2; ++mt)
    #pragma unroll
    for (int nt = 0; nt < 4; ++nt)
      #pragma unroll
      for (int r = 0; r < 4; ++r){
        int b = mt * 16 + quad * 4 + r;
        int n = nblk * 256 + wave * 64 + nt * 16 + l15;
        Y[(size_t)b * (S_ * 1024) + (size_t)tstep * 1024 + n] = acc[mt][nt][r] + bout[n];
      }
}

__global__ void copy_hidden_kernel(const float* __restrict__ HTf, float* __restrict__ out2){
  int idx = blockIdx.x * blockDim.x + threadIdx.x;  // 3*32*1024 exact
  int h = idx & 1023;
  int b = (idx >> 10) & 31;
  int v = idx >> 15;
  out2[((size_t)b * L_ + v) * 1024 + h] = HTf[(size_t)((S_ + v) & 7) * BH + b * H_ + h];
}

// ---------------------------------------------------------------------------
extern "C" void kernel_launch(void* const* d_in, const int* in_sizes, int n_in,
                              void* d_out, int out_size, void* d_ws, size_t ws_size,
                              hipStream_t stream){
  (void)in_sizes; (void)n_in; (void)out_size;
  const float* x    = (const float*)d_in[0];
  const float* h0   = (const float*)d_in[1];
  const float* Wx   = (const float*)d_in[2];
  const float* Wz   = (const float*)d_in[3];
  const float* bz   = (const float*)d_in[4];
  const float* Wr   = (const float*)d_in[5];
  const float* Wh   = (const float*)d_in[6];
  const float* br   = (const float*)d_in[7];
  const float* Wg   = (const float*)d_in[8];
  const float* Whg  = (const float*)d_in[9];
  const float* bg   = (const float*)d_in[10];
  const float* Wout = (const float*)d_in[11];
  const float* bout = (const float*)d_in[12];
  float* out = (float*)d_out;

  char* p = (char*)d_ws;
  unsigned short* WAp   = (unsigned short*)p; p += (size_t)384 * 32768 * 2;
  unsigned short* WBp   = (unsigned short*)p; p += (size_t)192 * 32768 * 2;
  unsigned short* WoutP = (unsigned short*)p; p += (size_t)64 * 32 * 64 * 8 * 2;
  unsigned short* Xp    = (unsigned short*)p; p += (size_t)S_ * PLANE * 2;
  unsigned short* HTb   = (unsigned short*)p; p += (size_t)(S_ + 3) * BH * 2;
  float*          HTf   = (float*)p;          p += (size_t)8 * BH * 4;
  unsigned short* hfinp = (unsigned short*)p; p += (size_t)8 * PLANE * 2;
  unsigned short* hL0p  = (unsigned short*)p; p += (size_t)4 * PLANE * 2;
  unsigned short* hL1p  = (unsigned short*)p; p += (size_t)4 * PLANE * 2;
  unsigned short* rsp   = (unsigned short*)p; p += (size_t)12 * PLANE * 2;
  float*          zbuf  = (float*)p;          p += (size_t)12 * BH * 4;
  unsigned*       cnt   = (unsigned*)p;       p += CNT_BYTES;
  if ((size_t)(p - (char*)d_ws) > ws_size) return;

  hipMemsetAsync(cnt, 0, CNT_BYTES, stream);
  prep_WA_packed  <<<6144, 256, 0, stream>>>(Wx, Wz, Wr, Wh, WAp);
  prep_WB_packed  <<<3072, 256, 0, stream>>>(Wg, Whg, WBp);
  prep_Wout_packed<<< 512, 256, 0, stream>>>(Wout, WoutP);
  prep_X_packed   <<<65536, 256, 0, stream>>>(x, Xp);
  prep_H0_kernel  <<<  384, 256, 0, stream>>>(h0, HTb, HTf, hfinp);

  gru_persist<<<NBLK, 128, 0, stream>>>(WAp, WBp, Xp, hL0p, hL1p, hfinp,
                                        HTb, HTf, zbuf, rsp, bz, br, bg, cnt);

  out_proj_kernel   <<<2048, 256, 0, stream>>>(HTb, WoutP, bout, out);
  copy_hidden_kernel<<< 384, 256, 0, stream>>>(HTf, out + (size_t)B_ * S_ * 1024);
}

// Round 12
// 7224.928 us; speedup vs baseline: 1.6646x; 1.6646x over previous
//
#include <hip/hip_runtime.h>

#define B_ 32
#define S_ 512
#define H_ 1024
#define L_ 3
#define BH (B_*H_)     // 32768
#define NBLK 512
#define PLANE 32768    // u16 elems in one A-frag-packed 32x1024 activation plane

typedef __attribute__((ext_vector_type(8))) short short8;
typedef __attribute__((ext_vector_type(4))) float f4;

__device__ __forceinline__ unsigned short f2bf(float f){
  unsigned int u = __float_as_uint(f);
  u += 0x7fffu + ((u >> 16) & 1u);   // RNE
  return (unsigned short)(u >> 16);
}
__device__ __forceinline__ float sigmoidf_(float x){
  return 1.0f / (1.0f + __expf(-x));
}
// offset (u16) of element (batch-row b, feature n) inside an A-frag-packed plane
// plane layout: [mh(2)][kb(32)][lane(64)][j(8)], lane = quad*16 + row
__device__ __forceinline__ int afrag_off(int b, int n){
  int mh = b >> 4, row = b & 15;
  int kb = n >> 5, quad = (n >> 3) & 3, j = n & 7;
  return (((mh * 32 + kb) * 64) + quad * 16 + row) * 8 + j;
}

// -------- device-coherent (agent scope) helpers -----------------------------
// sc1 global_load_dwordx4 = agent-scope 16B load (IC-coherent); hand-pipelined
// with counted vmcnt. The GEMM regions contain only these asm loads.
template<bool DC>
__device__ __forceinline__ short8 ldA(const unsigned short* p){
  short8 v;
  if constexpr (DC)
    asm volatile("global_load_dwordx4 %0, %1, off sc1" : "=&v"(v) : "v"(p));
  else
    asm volatile("global_load_dwordx4 %0, %1, off" : "=&v"(v) : "v"(p));
  return v;
}
template<int N>
__device__ __forceinline__ void waitv(){
  asm volatile("s_waitcnt vmcnt(%0)" :: "i"(N));
  __builtin_amdgcn_sched_barrier(0);   // rule #18: keep consumers below the wait
}
__device__ __forceinline__ float ldf_dc(const float* p){
  return __hip_atomic_load(p, __ATOMIC_RELAXED, __HIP_MEMORY_SCOPE_AGENT);
}
__device__ __forceinline__ void stf_dc(float* p, float v){
  __hip_atomic_store(p, v, __ATOMIC_RELAXED, __HIP_MEMORY_SCOPE_AGENT);
}
__device__ __forceinline__ void stu16_dc(unsigned short* p, unsigned short v){
  __hip_atomic_store(p, v, __ATOMIC_RELAXED, __HIP_MEMORY_SCOPE_AGENT);
}

// ---------------- prep: pack weights in MFMA-fragment order -----------------
__global__ void prep_WA_packed(const float* __restrict__ Wx, const float* __restrict__ Wz,
                               const float* __restrict__ Wr, const float* __restrict__ Wh,
                               unsigned short* __restrict__ WAp){
  int idx = blockIdx.x * blockDim.x + threadIdx.x;  // 384*64*64 exact
  int lane = idx & 63;
  int kb = (idx >> 6) & 63;
  int tile = idx >> 12;
  int g = tile >> 7, jt = tile & 127;
  int quad = lane >> 4, l15 = lane & 15;
  int n = jt * 16 + l15;
  int k0 = kb * 32 + quad * 8;
  int col = n & 1023;
  const float* W = (k0 < 1024) ? ((n < 1024) ? Wx : Wr) : ((n < 1024) ? Wz : Wh);
  const float* src = W + ((size_t)g * 1024 + (k0 & 1023)) * 1024 + col;
  short8 v;
  #pragma unroll
  for (int j = 0; j < 8; ++j) v[j] = (short)f2bf(src[(size_t)j * 1024]);
  *(short8*)(WAp + (size_t)idx * 8) = v;
}

__global__ void prep_WB_packed(const float* __restrict__ Wg, const float* __restrict__ Whg,
                               unsigned short* __restrict__ WBp){
  int idx = blockIdx.x * blockDim.x + threadIdx.x;  // 192*64*64 exact
  int lane = idx & 63;
  int kb = (idx >> 6) & 63;
  int tile = idx >> 12;
  int g = tile >> 6, jt = tile & 63;
  int quad = lane >> 4, l15 = lane & 15;
  int n = jt * 16 + l15;
  int k0 = kb * 32 + quad * 8;
  const float* W = (k0 < 1024) ? Wg : Whg;
  const float* src = W + ((size_t)g * 1024 + (k0 & 1023)) * 1024 + n;
  short8 v;
  #pragma unroll
  for (int j = 0; j < 8; ++j) v[j] = (short)f2bf(src[(size_t)j * 1024]);
  *(short8*)(WBp + (size_t)idx * 8) = v;
}

__global__ void prep_Wout_packed(const float* __restrict__ Wout,
                                 unsigned short* __restrict__ WoutP){
  int idx = blockIdx.x * blockDim.x + threadIdx.x;  // 64*32*64 exact
  int lane = idx & 63;
  int kb = (idx >> 6) & 31;
  int tile = idx >> 11;
  int quad = lane >> 4, l15 = lane & 15;
  int n = tile * 16 + l15;
  int k0 = kb * 32 + quad * 8;
  const float* src = Wout + (size_t)k0 * 1024 + n;
  short8 v;
  #pragma unroll
  for (int j = 0; j < 8; ++j) v[j] = (short)f2bf(src[(size_t)j * 1024]);
  *(short8*)(WoutP + (size_t)idx * 8) = v;
}

__global__ void prep_X_packed(const float* __restrict__ x, unsigned short* __restrict__ Xp){
  size_t idx = (size_t)blockIdx.x * blockDim.x + threadIdx.x;  // 512*32768 exact
  int j = (int)(idx & 7);
  int lane = (int)((idx >> 3) & 63);
  int kb = (int)((idx >> 9) & 31);
  int mh = (int)((idx >> 14) & 1);
  int t = (int)(idx >> 15);
  int b = mh * 16 + (lane & 15);
  int i = kb * 32 + (lane >> 4) * 8 + j;
  Xp[idx] = f2bf(x[((size_t)b * S_ + t) * 1024 + i]);
}

__global__ void prep_H0_kernel(const float* __restrict__ h0,
                               unsigned short* __restrict__ HTb, float* __restrict__ HTf,
                               unsigned short* __restrict__ hfinp){
  int idx = blockIdx.x * blockDim.x + threadIdx.x;  // 3*32*1024 exact
  int h = idx & 1023;
  int b = (idx >> 10) & 31;
  int v = idx >> 15;
  float val = h0[((size_t)b * L_ + v) * 1024 + h];
  HTb[idx] = f2bf(val);
  HTf[idx] = val;                              // ring slot v&7 == v for v<3
  hfinp[(size_t)v * PLANE + afrag_off(b, h)] = f2bf(val);
}

// ---------------- cheap monotonic tree barrier (R8-proven, verbatim) --------
// bar layout (uints): sub[x] at x*16 (x=0..7), top at 128, gen at 144.
// No cache maintenance: all cross-block data moves via agent-scope loads/
// stores coherent at the IC. __syncthreads drains vmcnt before arrival.
__device__ __forceinline__ void tree_barrier(unsigned* bar, unsigned target){
  __syncthreads();   // drains vmcnt for all waves of this block
  if (threadIdx.x == 0){
    unsigned* sub = bar + (blockIdx.x & 7) * 16;
    unsigned* top = bar + 128;
    unsigned* gen = bar + 144;
    unsigned old = __hip_atomic_fetch_add(sub, 1u, __ATOMIC_RELAXED, __HIP_MEMORY_SCOPE_AGENT);
    if (old == target * (NBLK / 8) - 1u){
      unsigned t2 = __hip_atomic_fetch_add(top, 1u, __ATOMIC_RELAXED, __HIP_MEMORY_SCOPE_AGENT);
      if (t2 == target * 8u - 1u)
        __hip_atomic_store(gen, target, __ATOMIC_RELAXED, __HIP_MEMORY_SCOPE_AGENT);
    }
    while (__hip_atomic_load(gen, __ATOMIC_RELAXED, __HIP_MEMORY_SCOPE_AGENT) < target)
      __builtin_amdgcn_s_sleep(1);
  }
  __syncthreads();
}

// ------- pipelined 64-step GEMM, LDS weights (batch 8, depth 4 = 32) --------
// The GEMM region contains only asm loads: first loop waits vmcnt(24) per
// batch; second drains 24/16/8/0. Exits at vmcnt(0). Accumulation order
// identical to R8 (inp kb0..31 then st kb32..63).
template<bool DCI>
__device__ __forceinline__ f4 gemm64_lds(const unsigned short* __restrict__ inp,
                                         const unsigned short* __restrict__ st,
                                         const unsigned short* w,   // LDS only
                                         int mh, int lane){
  const unsigned short* pi = inp + mh * 16384 + lane * 8;
  const unsigned short* ps = st  + mh * 16384 + lane * 8;
  short8 ab[4][8];
  #pragma unroll
  for (int b = 0; b < 4; ++b)
    #pragma unroll
    for (int j = 0; j < 8; ++j)
      ab[b][j] = ldA<DCI>(pi + (size_t)(b * 8 + j) * 512);
  f4 acc = {0.f, 0.f, 0.f, 0.f};
  #pragma unroll
  for (int b = 0; b < 4; ++b){
    short8 wv[8];                              // ds_reads issued BEFORE the wait
    #pragma unroll
    for (int j = 0; j < 8; ++j)
      wv[j] = *(const short8*)(w + (size_t)((b * 8 + j) * 64 + lane) * 8);
    waitv<24>();                               // batch b (inp) landed
    #pragma unroll
    for (int j = 0; j < 8; ++j)
      acc = __builtin_amdgcn_mfma_f32_16x16x32_bf16(ab[b][j], wv[j], acc, 0, 0, 0);
    #pragma unroll
    for (int j = 0; j < 8; ++j)                // refill slot with st batch b
      ab[b][j] = ldA<true>(ps + (size_t)(b * 8 + j) * 512);
  }
  #pragma unroll
  for (int b = 0; b < 4; ++b){
    short8 wv[8];
    #pragma unroll
    for (int j = 0; j < 8; ++j)
      wv[j] = *(const short8*)(w + (size_t)((32 + b * 8 + j) * 64 + lane) * 8);
    if (b == 0) waitv<24>();
    else if (b == 1) waitv<16>();
    else if (b == 2) waitv<8>();
    else waitv<0>();
    #pragma unroll
    for (int j = 0; j < 8; ++j)
      acc = __builtin_amdgcn_mfma_f32_16x16x32_bf16(ab[b][j], wv[j], acc, 0, 0, 0);
  }
  return acc;
}

// ------- pipelined 32-step half-GEMM for split B(2) -------------------------
// One wave: 32 DC A-loads + 32 plain W-loads (L2-resident read-only), batch
// 8A+8W = 16 vm ops, depth 2 = 32 in flight; waits 16,16,16,0. Exits vmcnt(0).
__device__ __forceinline__ f4 gemm32_half(const unsigned short* __restrict__ aP,
                                          const unsigned short* __restrict__ wP){
  short8 ab[2][8], wb[2][8];
  #pragma unroll
  for (int b = 0; b < 2; ++b){
    #pragma unroll
    for (int j = 0; j < 8; ++j) ab[b][j] = ldA<true>(aP + (size_t)(b * 8 + j) * 512);
    #pragma unroll
    for (int j = 0; j < 8; ++j) wb[b][j] = ldA<false>(wP + (size_t)(b * 8 + j) * 512);
  }
  f4 acc = {0.f, 0.f, 0.f, 0.f};
  #pragma unroll
  for (int b = 0; b < 4; ++b){
    if (b < 3) waitv<16>(); else waitv<0>();
    #pragma unroll
    for (int j = 0; j < 8; ++j)
      acc = __builtin_amdgcn_mfma_f32_16x16x32_bf16(ab[b & 1][j], wb[b & 1][j], acc, 0, 0, 0);
    if (b < 2){
      const int nb = b + 2;
      #pragma unroll
      for (int j = 0; j < 8; ++j) ab[b & 1][j] = ldA<true>(aP + (size_t)(nb * 8 + j) * 512);
      #pragma unroll
      for (int j = 0; j < 8; ++j) wb[b & 1][j] = ldA<false>(wP + (size_t)(nb * 8 + j) * 512);
    }
  }
  return acc;
}

// ---------------- persistent recurrence: LDS-resident weights ---------------
// 512 blocks x 128 threads (2 waves). 65 KB LDS/block = 2 blocks/CU.
// Blocks 0..383: A-tile (g=blk>>7, jt=blk&127) in LDS.
// Blocks 384..511: B-tile g=0,1 ((blk-384)>>6, jt&63) in LDS.
// Blocks 0..127 ADDITIONALLY run B(2) in B-phases (idle there otherwise):
// block i: tile jt2=i&63, batch-half bh=i>>6; wave0 = inp x Wg (kb 0..31),
// wave1 = rs x Whg (kb 32..63); partials combined via LDS. W streamed from
// global (plain loads -> per-XCD L2). Every working wave in every phase now
// issues exactly 64 vmem loads -> no straggler at the barrier.
// Schedule (slot assignments, ring depths) is identical to R8.
__global__ __launch_bounds__(128) void gru_persist(
    const unsigned short* __restrict__ WAp, const unsigned short* __restrict__ WBp,
    const unsigned short* __restrict__ Xp,
    unsigned short* __restrict__ hL0p, unsigned short* __restrict__ hL1p,
    unsigned short* __restrict__ hfinp,
    unsigned short* __restrict__ HTb, float* __restrict__ HTf,
    float* __restrict__ zbuf, unsigned short* __restrict__ rsp,
    const float* __restrict__ bz, const float* __restrict__ br,
    const float* __restrict__ bg, unsigned* bar)
{
  __shared__ unsigned short ldsw[32768];   // 64 KB weight tile
  __shared__ f4 part[64];                  // 1 KB B(2) K-split partials
  const int blk = blockIdx.x;
  const int lane = threadIdx.x & 63;
  const int mh = threadIdx.x >> 6;         // wave id; batch half for A/B roles
  const int quad = lane >> 4, l15 = lane & 15;

  // bootstrap: copy this block's weight tile into LDS (coalesced 16B/lane)
  {
    const unsigned short* src = (blk < 384) ? WAp + (size_t)blk * 32768
                                            : WBp + (size_t)(blk - 384) * 32768;
    for (int i = threadIdx.x; i < 4096; i += 128)
      *(short8*)(ldsw + (size_t)i * 8) = *(const short8*)(src + (size_t)i * 8);
  }
  __syncthreads();

  const int gA = blk >> 7, jtA = blk & 127;
  int gB = -1, jtB = 0;
  if (blk >= 384){ gB = (blk - 384) >> 6; jtB = (blk - 384) & 63; }

  // B(2) split assignment for blocks 0..127
  const bool isB2 = blk < 128;
  const int jt2 = blk & 63, bh2 = (blk >> 6) & 1;
  const unsigned short* w2 = WBp + (size_t)(128 + jt2) * 32768;

  // hoisted per-thread biases (fixed columns per block)
  float biasA = 0.f, biasB = 0.f, bias2 = 0.f;
  if (blk < 384){
    int n2 = jtA * 16 + l15;
    biasA = (jtA < 64) ? bz[gA * H_ + n2] : br[gA * H_ + n2 - 1024];
  }
  if (gB >= 0) biasB = bg[gB * H_ + jtB * 16 + l15];
  if (isB2)   bias2 = bg[2 * H_ + jt2 * 16 + l15];

  unsigned tgt = 1;
  for (int s = -4; s <= 2 * S_ - 1; ++s){
    int u = ((s & 1) ? (s - 1) : s) / 2;   // exact
    int v = u + 2;                          // state index this slot
    if (!(s & 1)){
      // ---------------- A phase ----------------
      if (blk < 384){
        int t = u + 2 - gA;
        if (t >= 0 && t < S_){
          int tm = t & 3;
          const unsigned short* inp = (gA == 0) ? Xp + (size_t)t * PLANE
                                    : (gA == 1) ? hL0p + (size_t)tm * PLANE
                                                : hL1p + (size_t)tm * PLANE;
          const unsigned short* st = hfinp + (size_t)(v & 7) * PLANE;
          f4 acc = (gA == 0) ? gemm64_lds<false>(inp, st, ldsw, mh, lane)
                             : gemm64_lds<true >(inp, st, ldsw, mh, lane);
          int n2 = jtA * 16 + l15;
          const float* sf = HTf + (size_t)(v & 7) * BH;
          if (jtA < 64){
            float* zb = zbuf + (size_t)(gA * 4 + tm) * BH;
            #pragma unroll
            for (int r = 0; r < 4; ++r){
              int b = mh * 16 + quad * 4 + r;
              stf_dc(zb + b * H_ + n2, sigmoidf_(acc[r] + biasA));
            }
          } else {
            int n = n2 - 1024;
            unsigned short* rp = rsp + (size_t)(gA * 4 + tm) * PLANE;
            #pragma unroll
            for (int r = 0; r < 4; ++r){
              int b = mh * 16 + quad * 4 + r;
              float sv = ldf_dc(sf + b * H_ + n);
              stu16_dc(rp + afrag_off(b, n), f2bf(sigmoidf_(acc[r] + biasA) * sv));
            }
          }
        }
      }
    } else {
      // ---------------- B phase ----------------
      if (gB >= 0){
        // pure B blocks, g = 0 or 1, LDS weights
        int t = u + 2 - gB;
        if (t >= 0 && t < S_){
          int tm = t & 3;
          const unsigned short* inp = (gB == 0) ? Xp + (size_t)t * PLANE
                                                : hL0p + (size_t)tm * PLANE;
          const unsigned short* rp = rsp + (size_t)(gB * 4 + tm) * PLANE;
          f4 acc = (gB == 0) ? gemm64_lds<false>(inp, rp, ldsw, mh, lane)
                             : gemm64_lds<true >(inp, rp, ldsw, mh, lane);
          int n = jtB * 16 + l15;
          const float* sf = HTf + (size_t)(v & 7) * BH;
          const float* zb = zbuf + (size_t)(gB * 4 + tm) * BH;
          #pragma unroll
          for (int r = 0; r < 4; ++r){
            int b = mh * 16 + quad * 4 + r;
            float gg = tanhf(acc[r] + biasB);
            float z = ldf_dc(zb + b * H_ + n);
            float sv = ldf_dc(sf + b * H_ + n);
            float h = z * sv + (1.f - z) * gg;
            unsigned short hb = f2bf(h);
            if (gB == 0) stu16_dc(hL0p + (size_t)tm * PLANE + afrag_off(b, n), hb);
            else         stu16_dc(hL1p + (size_t)tm * PLANE + afrag_off(b, n), hb);
          }
        }
      } else if (isB2){
        // split B(2): t = u (same slot as R8's dual-role B(2));
        // wave mh=0 -> inp x Wg (kb 0..31), mh=1 -> rs x Whg (kb 32..63)
        int t = u;
        if (t >= 0 && t < S_){
          int tm = t & 3;
          const unsigned short* aPlane = (mh == 0) ? hL1p + (size_t)tm * PLANE
                                                   : rsp + (size_t)(8 + tm) * PLANE;
          const unsigned short* aP = aPlane + bh2 * 16384 + lane * 8;
          const unsigned short* wP = w2 + mh * 16384 + lane * 8;
          f4 acc = gemm32_half(aP, wP);
          if (mh == 1) part[lane] = acc;
          __syncthreads();
          if (mh == 0){
            f4 p2 = part[lane];
            #pragma unroll
            for (int i = 0; i < 4; ++i) acc[i] += p2[i];
            int n = jt2 * 16 + l15;
            const float* sf = HTf + (size_t)((t + 2) & 7) * BH;
            const float* zb = zbuf + (size_t)(8 + tm) * BH;
            #pragma unroll
            for (int r = 0; r < 4; ++r){
              int b = bh2 * 16 + quad * 4 + r;
              float gg = tanhf(acc[r] + bias2);
              float z = ldf_dc(zb + b * H_ + n);
              float sv = ldf_dc(sf + b * H_ + n);
              float h = z * sv + (1.f - z) * gg;
              unsigned short hb = f2bf(h);
              stf_dc(HTf + (size_t)((t + 3) & 7) * BH + b * H_ + n, h);
              HTb[(size_t)(t + 3) * BH + b * H_ + n] = hb;   // read post-kernel only
              stu16_dc(hfinp + (size_t)((t + 3) & 7) * PLANE + afrag_off(b, n), hb);
            }
          }
        }
      }
    }
    tree_barrier(bar, tgt++);
  }
}

// ---------------- epilogue: Y = HT @ Wout + bout ----------------------------
__global__ __launch_bounds__(256) void out_proj_kernel(
    const unsigned short* __restrict__ HTb, const unsigned short* __restrict__ WoutP,
    const float* __restrict__ bout, float* __restrict__ Y){
  int tstep = blockIdx.x >> 2;
  int nblk  = blockIdx.x & 3;
  int wave = threadIdx.x >> 6, lane = threadIdx.x & 63;
  int quad = lane >> 4, l15 = lane & 15;
  const unsigned short* A = HTb + (size_t)(tstep + 3) * BH;
  f4 acc[2][4] = {};
  for (int kk = 0; kk < 32; ++kk){
    int k0 = kk * 32 + quad * 8;
    short8 a0 = *(const short8*)(A + l15 * H_ + k0);
    short8 a1 = *(const short8*)(A + (l15 + 16) * H_ + k0);
    #pragma unroll
    for (int nt = 0; nt < 4; ++nt){
      int tile = nblk * 16 + wave * 4 + nt;
      short8 bv = ((const short8*)WoutP)[((size_t)tile * 32 + kk) * 64 + lane];
      acc[0][nt] = __builtin_amdgcn_mfma_f32_16x16x32_bf16(a0, bv, acc[0][nt], 0, 0, 0);
      acc[1][nt] = __builtin_amdgcn_mfma_f32_16x16x32_bf16(a1, bv, acc[1][nt], 0, 0, 0);
    }
  }
  #pragma unroll
  for (int mt = 0; mt < 2; ++mt)
    #pragma unroll
    for (int nt = 0; nt < 4; ++nt)
      #pragma unroll
      for (int r = 0; r < 4; ++r){
        int b = mt * 16 + quad * 4 + r;
        int n = nblk * 256 + wave * 64 + nt * 16 + l15;
        Y[(size_t)b * (S_ * 1024) + (size_t)tstep * 1024 + n] = acc[mt][nt][r] + bout[n];
      }
}

__global__ void copy_hidden_kernel(const float* __restrict__ HTf, float* __restrict__ out2){
  int idx = blockIdx.x * blockDim.x + threadIdx.x;  // 3*32*1024 exact
  int h = idx & 1023;
  int b = (idx >> 10) & 31;
  int v = idx >> 15;
  out2[((size_t)b * L_ + v) * 1024 + h] = HTf[(size_t)((S_ + v) & 7) * BH + b * H_ + h];
}

// ---------------------------------------------------------------------------
extern "C" void kernel_launch(void* const* d_in, const int* in_sizes, int n_in,
                              void* d_out, int out_size, void* d_ws, size_t ws_size,
                              hipStream_t stream){
  (void)in_sizes; (void)n_in; (void)out_size;
  const float* x    = (const float*)d_in[0];
  const float* h0   = (const float*)d_in[1];
  const float* Wx   = (const float*)d_in[2];
  const float* Wz   = (const float*)d_in[3];
  const float* bz   = (const float*)d_in[4];
  const float* Wr   = (const float*)d_in[5];
  const float* Wh   = (const float*)d_in[6];
  const float* br   = (const float*)d_in[7];
  const float* Wg   = (const float*)d_in[8];
  const float* Whg  = (const float*)d_in[9];
  const float* bg   = (const float*)d_in[10];
  const float* Wout = (const float*)d_in[11];
  const float* bout = (const float*)d_in[12];
  float* out = (float*)d_out;

  char* p = (char*)d_ws;
  unsigned short* WAp   = (unsigned short*)p; p += (size_t)384 * 32768 * 2;
  unsigned short* WBp   = (unsigned short*)p; p += (size_t)192 * 32768 * 2;
  unsigned short* WoutP = (unsigned short*)p; p += (size_t)64 * 32 * 64 * 8 * 2;
  unsigned short* Xp    = (unsigned short*)p; p += (size_t)S_ * PLANE * 2;
  unsigned short* HTb   = (unsigned short*)p; p += (size_t)(S_ + 3) * BH * 2;
  float*          HTf   = (float*)p;          p += (size_t)8 * BH * 4;
  unsigned short* hfinp = (unsigned short*)p; p += (size_t)8 * PLANE * 2;
  unsigned short* hL0p  = (unsigned short*)p; p += (size_t)4 * PLANE * 2;
  unsigned short* hL1p  = (unsigned short*)p; p += (size_t)4 * PLANE * 2;
  unsigned short* rsp   = (unsigned short*)p; p += (size_t)12 * PLANE * 2;
  float*          zbuf  = (float*)p;          p += (size_t)12 * BH * 4;
  unsigned*       bar   = (unsigned*)p;       p += 4096;
  if ((size_t)(p - (char*)d_ws) > ws_size) return;

  hipMemsetAsync(bar, 0, 4096, stream);
  prep_WA_packed  <<<6144, 256, 0, stream>>>(Wx, Wz, Wr, Wh, WAp);
  prep_WB_packed  <<<3072, 256, 0, stream>>>(Wg, Whg, WBp);
  prep_Wout_packed<<< 512, 256, 0, stream>>>(Wout, WoutP);
  prep_X_packed   <<<65536, 256, 0, stream>>>(x, Xp);
  prep_H0_kernel  <<<  384, 256, 0, stream>>>(h0, HTb, HTf, hfinp);

  gru_persist<<<NBLK, 128, 0, stream>>>(WAp, WBp, Xp, hL0p, hL1p, hfinp,
                                        HTb, HTf, zbuf, rsp, bz, br, bg, bar);

  out_proj_kernel   <<<2048, 256, 0, stream>>>(HTb, WoutP, bout, out);
  copy_hidden_kernel<<< 384, 256, 0, stream>>>(HTf, out + (size_t)B_ * S_ * 1024);
}